// Round 4
// baseline (813.356 us; speedup 1.0000x reference)
//
#include <hip/hip_runtime.h>
#include <cstdint>
#include <cstddef>

typedef unsigned short u16;
typedef __bf16 bf16x8 __attribute__((ext_vector_type(8)));
typedef float f32x4 __attribute__((ext_vector_type(4)));
typedef u16 u16x8 __attribute__((ext_vector_type(8)));

#define B_DIM 4096
#define H_DIM 2048
#define BH 8388608  // B_DIM * H_DIM

__device__ __forceinline__ float b2f(u16 x) {
  union { uint32_t u; float f; } v;
  v.u = ((uint32_t)x) << 16;
  return v.f;
}
__device__ __forceinline__ u16 f2b(float f) {
  union { float f; uint32_t u; } v;
  v.f = f;
  uint32_t r = v.u + 0x7FFFu + ((v.u >> 16) & 1u);
  return (u16)(r >> 16);
}
__device__ __forceinline__ float sigm(float x) { return 1.0f / (1.0f + __expf(-x)); }

typedef __attribute__((address_space(1))) void gv_t;
typedef __attribute__((address_space(3))) void lv_t;
__device__ __forceinline__ void g2lds16(const void* g, void* l) {
  __builtin_amdgcn_global_load_lds((gv_t*)g, (lv_t*)l, 16, 0, 0);
}

#define MFMA_BF16 __builtin_amdgcn_mfma_f32_16x16x32_bf16

#define FENCE asm volatile("" ::: "memory")
#define BARRIER do { FENCE; __builtin_amdgcn_s_barrier(); FENCE; } while (0)
#define LGKM0 do { asm volatile("s_waitcnt lgkmcnt(0)" ::: "memory"); \
                   __builtin_amdgcn_sched_barrier(0); } while (0)
#define LGKM8 asm volatile("s_waitcnt lgkmcnt(8)" ::: "memory")
#define VMCNT2 asm volatile("s_waitcnt vmcnt(2)" ::: "memory")
#define VMCNT4 asm volatile("s_waitcnt vmcnt(4)" ::: "memory")
#define VMCNT0 asm volatile("s_waitcnt vmcnt(0)" ::: "memory")
#define PRIO1 __builtin_amdgcn_s_setprio(1)
#define PRIO0 __builtin_amdgcn_s_setprio(0)

// ---------------- fp32 -> bf16 activation convert ----------------
struct CvtParams { const float* src[3]; u16* dst[3]; };

__global__ __launch_bounds__(256) void cvt_k(CvtParams p) {
  const float* __restrict__ s = p.src[blockIdx.y];
  u16* __restrict__ d = p.dst[blockIdx.y];
  size_t idx = ((size_t)blockIdx.x * 256 + threadIdx.x) * 8;
  float4 a = *(const float4*)(s + idx);
  float4 b = *(const float4*)(s + idx + 4);
  u16x8 o;
  o[0] = f2b(a.x); o[1] = f2b(a.y); o[2] = f2b(a.z); o[3] = f2b(a.w);
  o[4] = f2b(b.x); o[5] = f2b(b.y); o[6] = f2b(b.z); o[7] = f2b(b.w);
  *(u16x8*)(d + idx) = o;
}

// ---------------- weight transpose+convert: Wt[n][k] = bf16(W[k][n]) ----------------
struct TransParams {
  const float* src[13];
  u16* dst[13];
  int dstride[13];
};

__global__ __launch_bounds__(256) void transpose_k(TransParams p) {
  __shared__ u16 lds[64][72];  // pitch 72 breaks bank aliasing
  const int mat = blockIdx.z;
  const float* __restrict__ src = p.src[mat];
  u16* __restrict__ dst = p.dst[mat];
  const int dstride = p.dstride[mat];
  const int tk = blockIdx.y * 64;
  const int tn = blockIdx.x * 64;
  const int t = threadIdx.x;
  const int lr = t >> 3;
  const int lc = (t & 7) * 8;
#pragma unroll
  for (int half = 0; half < 2; half++) {
    int r = lr + half * 32;
    const float4* g = (const float4*)(src + (size_t)(tk + r) * 2048 + tn + lc);
    float4 a = g[0], b = g[1];
    u16x8 t8;
    t8[0] = f2b(a.x); t8[1] = f2b(a.y); t8[2] = f2b(a.z); t8[3] = f2b(a.w);
    t8[4] = f2b(b.x); t8[5] = f2b(b.y); t8[6] = f2b(b.z); t8[7] = f2b(b.w);
    *(u16x8*)&lds[r][lc] = t8;
  }
  __syncthreads();
#pragma unroll
  for (int half = 0; half < 2; half++) {
    int n = lr + half * 32;
    u16x8 tmp;
#pragma unroll
    for (int j = 0; j < 8; j++) tmp[j] = lds[lc + j][n];
    *(u16x8*)(dst + (size_t)(tn + n) * dstride + tk + lc) = tmp;
  }
}

// ---------------- m201-style 8-phase (NF=4) / 4-phase (NF=2) pipelined K-loop ----------
// BM=256, BN=64*NF, BK=64, 8 waves (2M x 4N). Buffers: buf0 <- even K-tiles,
// buf1 <- odd K-tiles (fixed parity, no alternation). Per-tile quadrants with
// register reuse: Q1 reads a03(8)+b01(4), Q2 reads a47(8), Q3 reads b23(4),
// Q4 reads 0. Region deaths (per buffer): A after Q2-phase barrier, B after
// Q3-phase barrier (NF=4) / after Q1-phase barrier (NF=2: b01 covers all B).
// NF=4 staging (2 loads/phase): ph1,2: B-odd(cur) -> buf1; ph3,4: A-even'
//   -> buf0; ph5,6: B-even' -> buf0; ph7,8: A-odd' -> buf1.
//   vmcnt(4) at ph4 (covers A-odd prev ph7,8 + B-odd ph1,2 before ph5 reads)
//   and ph8 (covers A-even' ph3,4 + B-even' ph5,6 before next ph1 reads);
//   every load has >=2 phases (~1200 cyc) of cover. Never drains to 0 in-loop.
// NF=2 staging: ph1: A-odd(cur) x4 -> buf1; ph2: B-even' x2 -> buf0;
//   ph3: A-even' x4 -> buf0; ph4: B-odd' x2 -> buf1. vmcnt(2) at ph2/ph4.
// Deadlock-free: uniform barrier count, no divergent barriers.
template <int NF>
__device__ __forceinline__ void kloop(
    const u16* __restrict__ A0, const u16* __restrict__ A1, const u16* __restrict__ A2,
    const u16* __restrict__ Wt, const int NT, const long Ktot,
    const int m0, const int n0,
    u16* lA0, u16* lA1, u16* lB0, u16* lB1,
    f32x4 (&acc)[8][NF]) {
  const int tid = threadIdx.x;
  const int wave = tid >> 6, lane = tid & 63;
  const int fm = lane & 15, fkc = lane >> 4;
  const int x7 = fm & 7;
  const int wm = (wave >> 2) * 128, wn = (wave & 3) * (NF * 16);
  const int lr = tid >> 3;                 // 0..63 row-in-round
  const int chunk = (tid & 7) ^ (lr & 7);  // pre-swizzled global k-chunk
  const int stageOff = wave * 512;         // wave*8 rows * 64 elems

  int raOff[8], rbOff[NF];
#pragma unroll
  for (int i = 0; i < 8; i++) raOff[i] = (wm + i * 16 + fm) * 64;
#pragma unroll
  for (int j = 0; j < NF; j++) rbOff[j] = (wn + j * 16 + fm) * 64;
  const int so0 = ((fkc ^ x7) << 3);        // ks0 chunk c=fkc
  const int so1 = (((4 + fkc) ^ x7) << 3);  // ks1 chunk c=4+fkc

  auto stA = [&](int tt, int r, u16* dstA) {
    const int seg = tt >> 5;
    const u16* base = (seg == 0) ? A0 : ((seg == 1) ? A1 : A2);
    g2lds16(base + (size_t)(m0 + r * 64 + lr) * 2048 + ((tt & 31) << 6) + (chunk << 3),
            dstA + r * 4096 + stageOff);
  };
  auto stB = [&](int tt, int r, u16* dstB) {
    g2lds16(Wt + (size_t)(n0 + r * 64 + lr) * Ktot + ((size_t)tt << 6) + (chunk << 3),
            dstB + r * 4096 + stageOff);
  };
  auto rdA = [&](const u16* l, bf16x8 (&d)[4][2], int base) {
#pragma unroll
    for (int i = 0; i < 4; i++) {
      d[i][0] = *(const bf16x8*)&l[raOff[base + i] + so0];
      d[i][1] = *(const bf16x8*)&l[raOff[base + i] + so1];
    }
  };
  auto rdB = [&](const u16* l, bf16x8 (&d)[2][2], int base) {
#pragma unroll
    for (int j = 0; j < 2; j++) {
      d[j][0] = *(const bf16x8*)&l[rbOff[base + j] + so0];
      d[j][1] = *(const bf16x8*)&l[rbOff[base + j] + so1];
    }
  };
  auto mfma16 = [&](bf16x8 (&a)[4][2], bf16x8 (&b)[2][2], int mi, int nj) {
#pragma unroll
    for (int ks = 0; ks < 2; ks++)
#pragma unroll
      for (int i = 0; i < 4; i++) {
        acc[mi + i][nj + 0] = MFMA_BF16(a[i][ks], b[0][ks], acc[mi + i][nj + 0], 0, 0, 0);
        acc[mi + i][nj + 1] = MFMA_BF16(a[i][ks], b[1][ks], acc[mi + i][nj + 1], 0, 0, 0);
      }
  };

  const int NI = NT >> 1;
  bf16x8 a03[4][2], a47[4][2], b01[2][2], b23[2][2];

  if constexpr (NF == 4) {
    // prologue: tile0 A+B -> buf0 (8), tile1 A -> buf1 (4); keep tile1-A in flight
#pragma unroll
    for (int r = 0; r < 4; r++) stA(0, r, lA0);
#pragma unroll
    for (int r = 0; r < 4; r++) stB(0, r, lB0);
#pragma unroll
    for (int r = 0; r < 4; r++) stA(1, r, lA1);
    VMCNT4;
    BARRIER;

    for (int it = 0; it < NI; ++it) {
      const int tE = 2 * it, tO = 2 * it + 1;
      const int tE2 = (tE + 2 < NT) ? tE + 2 : NT - 1;
      const int tO2 = (tO + 2 < NT) ? tO + 2 : NT - 1;
      // ---- ph1: Q1-E
      rdA(lA0, a03, 0); rdB(lB0, b01, 0);
      stB(tO, 0, lB1); stB(tO, 1, lB1);
      LGKM8;
      BARRIER; LGKM0;
      PRIO1; mfma16(a03, b01, 0, 0); PRIO0;
      BARRIER;
      // ---- ph2: Q2-E
      rdA(lA0, a47, 4);
      stB(tO, 2, lB1); stB(tO, 3, lB1);
      BARRIER; LGKM0;
      PRIO1; mfma16(a47, b01, 4, 0); PRIO0;
      BARRIER;
      // ---- ph3: Q3-E (buf0-A dead)
      rdB(lB0, b23, 2);
      stA(tE2, 0, lA0); stA(tE2, 1, lA0);
      BARRIER; LGKM0;
      PRIO1; mfma16(a03, b23, 0, 2); PRIO0;
      BARRIER;
      // ---- ph4: Q4-E (no reads; buf0-A dead)
      stA(tE2, 2, lA0); stA(tE2, 3, lA0);
      BARRIER;
      PRIO1; mfma16(a47, b23, 4, 2); PRIO0;
      VMCNT4;  // drains A-odd(ph7,8 prev) + B-odd(ph1,2); keeps A-even'(ph3,4)
      BARRIER;
      // ---- ph5: Q1-O (buf0-B dead)
      rdA(lA1, a03, 0); rdB(lB1, b01, 0);
      stB(tE2, 0, lB0); stB(tE2, 1, lB0);
      LGKM8;
      BARRIER; LGKM0;
      PRIO1; mfma16(a03, b01, 0, 0); PRIO0;
      BARRIER;
      // ---- ph6: Q2-O
      rdA(lA1, a47, 4);
      stB(tE2, 2, lB0); stB(tE2, 3, lB0);
      BARRIER; LGKM0;
      PRIO1; mfma16(a47, b01, 4, 0); PRIO0;
      BARRIER;
      // ---- ph7: Q3-O (buf1-A dead)
      rdB(lB1, b23, 2);
      stA(tO2, 0, lA1); stA(tO2, 1, lA1);
      BARRIER; LGKM0;
      PRIO1; mfma16(a03, b23, 0, 2); PRIO0;
      BARRIER;
      // ---- ph8: Q4-O
      stA(tO2, 2, lA1); stA(tO2, 3, lA1);
      BARRIER;
      PRIO1; mfma16(a47, b23, 4, 2); PRIO0;
      VMCNT4;  // drains A-even'(ph3,4) + B-even'(ph5,6); keeps A-odd'(ph7,8)
      BARRIER;
    }
  } else {
    // NF == 2: 4-phase. prologue: tile0 A+B -> buf0 (6), tile1 B -> buf1 (2)
#pragma unroll
    for (int r = 0; r < 4; r++) stA(0, r, lA0);
    stB(0, 0, lB0); stB(0, 1, lB0);
    stB(1, 0, lB1); stB(1, 1, lB1);
    VMCNT2;
    BARRIER;

    for (int it = 0; it < NI; ++it) {
      const int tE = 2 * it, tO = 2 * it + 1;
      const int tE2 = (tE + 2 < NT) ? tE + 2 : NT - 1;
      const int tO2 = (tO + 2 < NT) ? tO + 2 : NT - 1;
      // ---- ph1: Q1-E; stage A-odd(cur) (buf1-A dead since prev ph4)
      rdA(lA0, a03, 0); rdB(lB0, b01, 0);
      stA(tO, 0, lA1); stA(tO, 1, lA1); stA(tO, 2, lA1); stA(tO, 3, lA1);
      LGKM8;
      BARRIER; LGKM0;
      PRIO1; mfma16(a03, b01, 0, 0); PRIO0;
      BARRIER;
      // ---- ph2: Q2-E; stage B-even' (buf0-B dead after ph1)
      rdA(lA0, a47, 4);
      stB(tE2, 0, lB0); stB(tE2, 1, lB0);
      BARRIER; LGKM0;
      PRIO1; mfma16(a47, b01, 4, 0); PRIO0;
      VMCNT2;  // drains B-odd(prev ph4) + A-odd(ph1); keeps B-even'(ph2)
      BARRIER;
      // ---- ph3: Q1-O; stage A-even' (buf0-A dead after ph2)
      rdA(lA1, a03, 0); rdB(lB1, b01, 0);
      stA(tE2, 0, lA0); stA(tE2, 1, lA0); stA(tE2, 2, lA0); stA(tE2, 3, lA0);
      LGKM8;
      BARRIER; LGKM0;
      PRIO1; mfma16(a03, b01, 0, 0); PRIO0;
      BARRIER;
      // ---- ph4: Q2-O; stage B-odd' (buf1-B dead after ph3)
      rdA(lA1, a47, 4);
      stB(tO2, 0, lB1); stB(tO2, 1, lB1);
      BARRIER; LGKM0;
      PRIO1; mfma16(a47, b01, 4, 0); PRIO0;
      VMCNT2;  // drains B-even'(ph2) + A-even'(ph3); keeps B-odd'(ph4)
      BARRIER;
    }
  }

  // no global_load_lds in flight at kernel end
  VMCNT0;
}

// ---------------- phase-1 GEMMs, big 4 gates (fused K; grid.z = gate) ----------------
struct Gemm256Desc {
  const u16* A0; const u16* A1; const u16* A2;
  const u16* Wt; u16* C; int nseg;
};
struct Gemm256Params { Gemm256Desc d[4]; };

__global__ __launch_bounds__(512, 2) void gemm256_multi(Gemm256Params p) {
  const Gemm256Desc d = p.d[blockIdx.z];
  __shared__ u16 lA[2][16384];
  __shared__ u16 lB[2][16384];
  // XCD-aware swizzle within the 128-block z-slice (bijective: 128 % 8 == 0)
  const int bid = blockIdx.y * 8 + blockIdx.x;
  const int swz = (bid & 7) * 16 + (bid >> 3);
  const int m0 = (swz >> 3) * 256, n0 = (swz & 7) * 256;
  const int NT = d.nseg << 5;
  const long Ktot = (long)NT << 6;

  f32x4 acc[8][4];
#pragma unroll
  for (int i = 0; i < 8; i++)
#pragma unroll
    for (int j = 0; j < 4; j++) acc[i][j] = (f32x4)0.0f;

  kloop<4>(d.A0, d.A1, d.A2, d.Wt, NT, Ktot, m0, n0, lA[0], lA[1], lB[0], lB[1], acc);

  const int lane = threadIdx.x & 63, wave = threadIdx.x >> 6;
  const int fm = lane & 15, quad = lane >> 4;
  const int wm = (wave >> 2) * 128, wn = (wave & 3) * 64;
#pragma unroll
  for (int i = 0; i < 8; i++)
#pragma unroll
    for (int j = 0; j < 4; j++)
#pragma unroll
      for (int r = 0; r < 4; r++) {
        size_t row = (size_t)(m0 + wm + i * 16 + quad * 4 + r);
        size_t col = (size_t)(n0 + wn + j * 16 + fm);
        d.C[row * 2048 + col] = f2b(acc[i][j][r]);
      }
}

// ---------------- R gate: zr = xb @ WtR^T, BN=128 (256 blocks -> 1/CU, balanced) -----
__global__ __launch_bounds__(512, 2) void gemm_r(
    const u16* __restrict__ A, const u16* __restrict__ Wt, u16* __restrict__ C) {
  __shared__ u16 lA[2][16384];
  __shared__ u16 lB[2][8192];
  const int bid = blockIdx.x;
  const int swz = (bid & 7) * 32 + (bid >> 3);  // bijective: 256 % 8 == 0
  const int m0 = (swz >> 4) * 256, n0 = (swz & 15) * 128;

  f32x4 acc[8][2];
#pragma unroll
  for (int i = 0; i < 8; i++)
#pragma unroll
    for (int j = 0; j < 2; j++) acc[i][j] = (f32x4)0.0f;

  kloop<2>(A, nullptr, nullptr, Wt, 32, 2048, m0, n0, lA[0], lA[1], lB[0], lB[1], acc);

  const int lane = threadIdx.x & 63, wave = threadIdx.x >> 6;
  const int fm = lane & 15, quad = lane >> 4;
  const int wm = (wave >> 2) * 128, wn = (wave & 3) * 32;
#pragma unroll
  for (int i = 0; i < 8; i++)
#pragma unroll
    for (int j = 0; j < 2; j++)
#pragma unroll
      for (int r = 0; r < 4; r++) {
        size_t row = (size_t)(m0 + wm + i * 16 + quad * 4 + r);
        size_t col = (size_t)(n0 + wn + j * 16 + fm);
        C[row * 2048 + col] = f2b(acc[i][j][r]);
      }
}

// ---------------- phase-3 GEMMs: z=0: t1=c@w_co (bf16); z=1: t2=tanh(c)@w_c (fp32) ----
struct GemmResParams {
  const u16* A[2]; const u16* W[2];
  u16* t1; float* t2;
};

__global__ __launch_bounds__(512, 2) void gemm256_res(GemmResParams p) {
  const int z = blockIdx.z;
  __shared__ u16 lA[2][16384];
  __shared__ u16 lB[2][16384];
  const int bid = blockIdx.y * 8 + blockIdx.x;
  const int swz = (bid & 7) * 16 + (bid >> 3);
  const int m0 = (swz >> 3) * 256, n0 = (swz & 7) * 256;

  f32x4 acc[8][4];
#pragma unroll
  for (int i = 0; i < 8; i++)
#pragma unroll
    for (int j = 0; j < 4; j++) acc[i][j] = (f32x4)0.0f;

  kloop<4>(p.A[z], nullptr, nullptr, p.W[z], 32, 2048, m0, n0, lA[0], lA[1], lB[0], lB[1], acc);

  const int lane = threadIdx.x & 63, wave = threadIdx.x >> 6;
  const int fm = lane & 15, quad = lane >> 4;
  const int wm = (wave >> 2) * 128, wn = (wave & 3) * 64;
  if (z == 0) {
#pragma unroll
    for (int i = 0; i < 8; i++)
#pragma unroll
      for (int j = 0; j < 4; j++)
#pragma unroll
        for (int r = 0; r < 4; r++) {
          size_t row = (size_t)(m0 + wm + i * 16 + quad * 4 + r);
          size_t col = (size_t)(n0 + wn + j * 16 + fm);
          p.t1[row * 2048 + col] = f2b(acc[i][j][r]);
        }
  } else {
#pragma unroll
    for (int i = 0; i < 8; i++)
#pragma unroll
      for (int j = 0; j < 4; j++)
#pragma unroll
        for (int r = 0; r < 4; r++) {
          size_t row = (size_t)(m0 + wm + i * 16 + quad * 4 + r);
          size_t col = (size_t)(n0 + wn + j * 16 + fm);
          p.t2[row * 2048 + col] = acc[i][j][r];
        }
  }
}

// ---------------- elementwise 1: gates -> c; stash bf16(c), bf16(tanh c) in-place ----------------
__global__ __launch_bounds__(256) void ew1_k(
    u16* __restrict__ zi, const u16* __restrict__ zf, u16* __restrict__ zg,
    const float* __restrict__ cprev, const float* __restrict__ bi,
    const float* __restrict__ bff, const float* __restrict__ bg,
    float* __restrict__ c_out) {
  size_t idx = ((size_t)blockIdx.x * 256 + threadIdx.x) * 8;
  int col = (int)(idx & (H_DIM - 1));
  u16x8 vzi = *(const u16x8*)(zi + idx);
  u16x8 vzf = *(const u16x8*)(zf + idx);
  u16x8 vzg = *(const u16x8*)(zg + idx);
  float4 cp0 = *(const float4*)(cprev + idx);
  float4 cp1 = *(const float4*)(cprev + idx + 4);
  float4 bi0 = *(const float4*)(bi + col), bi1 = *(const float4*)(bi + col + 4);
  float4 bf0 = *(const float4*)(bff + col), bf1 = *(const float4*)(bff + col + 4);
  float4 bg0 = *(const float4*)(bg + col), bg1 = *(const float4*)(bg + col + 4);
  float cpv[8] = {cp0.x, cp0.y, cp0.z, cp0.w, cp1.x, cp1.y, cp1.z, cp1.w};
  float biv[8] = {bi0.x, bi0.y, bi0.z, bi0.w, bi1.x, bi1.y, bi1.z, bi1.w};
  float bfv[8] = {bf0.x, bf0.y, bf0.z, bf0.w, bf1.x, bf1.y, bf1.z, bf1.w};
  float bgv[8] = {bg0.x, bg0.y, bg0.z, bg0.w, bg1.x, bg1.y, bg1.z, bg1.w};
  float cv[8], tcv[8];
#pragma unroll
  for (int e = 0; e < 8; e++) {
    float iv = b2f(vzi[e]) + biv[e];
    float fv = b2f(vzf[e]) + bfv[e];
    float gv = b2f(vzg[e]) + bgv[e];
    float c = sigm(fv) * cpv[e] + sigm(iv) * tanhf(gv);
    cv[e] = c;
    tcv[e] = tanhf(c);
  }
  u16x8 cb8, tc8;
#pragma unroll
  for (int e = 0; e < 8; e++) { cb8[e] = f2b(cv[e]); tc8[e] = f2b(tcv[e]); }
  *(u16x8*)(zi + idx) = cb8;   // bf16(c) for c @ w_co
  *(u16x8*)(zg + idx) = tc8;   // bf16(tanh c) for tanh(c) @ w_c
  float4 c0 = {cv[0], cv[1], cv[2], cv[3]}, c1 = {cv[4], cv[5], cv[6], cv[7]};
  *(float4*)(c_out + idx) = c0;
  *(float4*)(c_out + idx + 4) = c1;
}

// ---------------- elementwise 2: h = tanh(zo + t1 + b_o) * (zr + t2) ----------------
__global__ __launch_bounds__(256) void ew2_k(
    const u16* __restrict__ zo, const u16* __restrict__ zr,
    const u16* __restrict__ t1, const float* __restrict__ t2,
    const float* __restrict__ bo, float* __restrict__ h) {
  size_t idx = ((size_t)blockIdx.x * 256 + threadIdx.x) * 8;
  int col = (int)(idx & (H_DIM - 1));
  u16x8 vo = *(const u16x8*)(zo + idx);
  u16x8 vr = *(const u16x8*)(zr + idx);
  u16x8 v1 = *(const u16x8*)(t1 + idx);
  float4 t2a = *(const float4*)(t2 + idx);
  float4 t2b = *(const float4*)(t2 + idx + 4);
  float4 bo0 = *(const float4*)(bo + col);
  float4 bo1 = *(const float4*)(bo + col + 4);
  float t2v[8] = {t2a.x, t2a.y, t2a.z, t2a.w, t2b.x, t2b.y, t2b.z, t2b.w};
  float bov[8] = {bo0.x, bo0.y, bo0.z, bo0.w, bo1.x, bo1.y, bo1.z, bo1.w};
  float hv[8];
#pragma unroll
  for (int e = 0; e < 8; e++) {
    float ov = b2f(vo[e]) + b2f(v1[e]) + bov[e];
    hv[e] = tanhf(ov) * (b2f(vr[e]) + t2v[e]);
  }
  float4 h0 = {hv[0], hv[1], hv[2], hv[3]}, h1 = {hv[4], hv[5], hv[6], hv[7]};
  *(float4*)(h + idx) = h0;
  *(float4*)(h + idx + 4) = h1;
}

// ---------------- launch ----------------
extern "C" void kernel_launch(void* const* d_in, const int* in_sizes, int n_in,
                              void* d_out, int out_size, void* d_ws, size_t ws_size,
                              hipStream_t stream) {
  const float* input_ = (const float*)d_in[0];
  const float* h_prev = (const float*)d_in[1];
  const float* c_prev = (const float*)d_in[2];
  const float* w_xi = (const float*)d_in[3];
  const float* w_hi = (const float*)d_in[4];
  const float* w_ci = (const float*)d_in[5];
  const float* w_xf = (const float*)d_in[6];
  const float* w_hf = (const float*)d_in[7];
  const float* w_cf = (const float*)d_in[8];
  const float* w_xg = (const float*)d_in[9];
  const float* w_hg = (const float*)d_in[10];
  const float* w_xo = (const float*)d_in[11];
  const float* w_ho = (const float*)d_in[12];
  const float* w_co = (const float*)d_in[13];
  const float* w_c  = (const float*)d_in[14];
  const float* w_i  = (const float*)d_in[15];
  const float* b_i  = (const float*)d_in[16];
  const float* b_f  = (const float*)d_in[17];
  const float* b_g  = (const float*)d_in[18];
  const float* b_o  = (const float*)d_in[19];

  u16* ws = (u16*)d_ws;
  u16* WtI  = ws;                          // 2048 x 6144  [n][k: xi|hi|ci]
  u16* WtF  = WtI  + (size_t)2048 * 6144;
  u16* WtG  = WtF  + (size_t)2048 * 6144;  // 2048 x 4096  [n][k: xg|hg]
  u16* WtO  = WtG  + (size_t)2048 * 4096;
  u16* WtR  = WtO  + (size_t)2048 * 4096;  // 2048 x 2048
  u16* WtCO = WtR  + (size_t)2048 * 2048;
  u16* WtC  = WtCO + (size_t)2048 * 2048;
  u16* zi   = WtC  + (size_t)2048 * 2048;  // [4096 x 2048] bf16 each
  u16* zf   = zi + (size_t)BH;
  u16* zg   = zf + (size_t)BH;
  u16* zo   = zg + (size_t)BH;
  u16* zr   = zo + (size_t)BH;

  // t1 (bf16) reuses WtG (dead after gemm256_multi; exactly BH elems).
  // t2 (fp32) reuses WtI+WtF (dead after gemm256_multi; 50 MB >= 33.6 MB).
  u16* t1buf = WtG;
  float* t2buf = (float*)WtI;

  u16* ob16 = (u16*)d_out;
  u16* xb = ob16;                  // bf16(input_)  — dead before h written
  u16* hb = ob16 + (size_t)BH;     // bf16(h_prev)
  u16* cb = ob16 + (size_t)2 * BH; // bf16(c_prev)  — dead before c written
  float* out_f = (float*)d_out;
  float* h_out = out_f;
  float* c_out = out_f + (size_t)BH;

  // 1. activations fp32 -> bf16
  CvtParams cp;
  cp.src[0] = input_; cp.src[1] = h_prev; cp.src[2] = c_prev;
  cp.dst[0] = xb; cp.dst[1] = hb; cp.dst[2] = cb;
  cvt_k<<<dim3(BH / 2048, 3), 256, 0, stream>>>(cp);

  // 2. weights fp32 -> bf16, transposed into fused-K layouts
  TransParams tp;
  const float* srcs[13] = {w_xi, w_hi, w_ci, w_xf, w_hf, w_cf, w_xg, w_hg, w_xo, w_ho, w_i, w_co, w_c};
  u16* dsts[13] = {WtI, WtI + 2048, WtI + 4096, WtF, WtF + 2048, WtF + 4096,
                   WtG, WtG + 2048, WtO, WtO + 2048, WtR, WtCO, WtC};
  int strides[13] = {6144, 6144, 6144, 6144, 6144, 6144, 4096, 4096, 4096, 4096, 2048, 2048, 2048};
  for (int i = 0; i < 13; i++) { tp.src[i] = srcs[i]; tp.dst[i] = dsts[i]; tp.dstride[i] = strides[i]; }
  transpose_k<<<dim3(32, 32, 13), 256, 0, stream>>>(tp);

  // 3a. phase-1 GEMMs, 4 big gates (512 blocks = exactly 2/CU, balanced rounds)
  Gemm256Params g1;
  g1.d[0] = {xb, hb, cb, WtI, zi, 3};
  g1.d[1] = {xb, hb, cb, WtF, zf, 3};
  g1.d[2] = {xb, hb, nullptr, WtG, zg, 2};
  g1.d[3] = {xb, hb, nullptr, WtO, zo, 2};
  gemm256_multi<<<dim3(8, 16, 4), 512, 0, stream>>>(g1);

  // 3b. R gate at BN=128 (256 blocks = exactly 1/CU, balanced)
  gemm_r<<<dim3(256), 512, 0, stream>>>(xb, WtR, zr);

  // 4. elementwise 1: c fp32 -> d_out; bf16(c) -> zi, bf16(tanh c) -> zg (in-place)
  ew1_k<<<dim3(BH / 2048), 256, 0, stream>>>(zi, zf, zg, c_prev, b_i, b_f, b_g, c_out);

  // 5. phase-3 GEMMs: z=0 t1 = c@w_co (bf16), z=1 t2 = tanh(c)@w_c (fp32)
  GemmResParams gr;
  gr.A[0] = zi; gr.A[1] = zg; gr.W[0] = WtCO; gr.W[1] = WtC;
  gr.t1 = t1buf; gr.t2 = t2buf;
  gemm256_res<<<dim3(8, 16, 2), 512, 0, stream>>>(gr);

  // 6. elementwise 2: h -> d_out
  ew2_k<<<dim3(BH / 2048), 256, 0, stream>>>(zo, zr, t1buf, t2buf, b_o, h_out);
}